// Round 5
// baseline (165.969 us; speedup 1.0000x reference)
//
#include <hip/hip_runtime.h>
#include <hip/hip_bf16.h>
#include <stdint.h>

#define S_LEN 4096
#define LOG2E 1.44269504088896f

typedef __attribute__((ext_vector_type(8)))  short short8;
typedef __attribute__((ext_vector_type(4)))  float f32x4;
typedef __attribute__((ext_vector_type(16))) float f32x16;
typedef __attribute__((ext_vector_type(2)))  unsigned int u32x2;
typedef __attribute__((ext_vector_type(4)))  unsigned int u32x4;

// workspace (bytes)
#define OFF_V     ((size_t)0)                        // [4][256][4096] bf16 = 8MB
#define OFF_QT_HI (OFF_V + (size_t)(8u<<20))         // [4][4096][32] = 1MB each
#define OFF_QT_LO (OFF_QT_HI + (size_t)(1u<<20))
#define OFF_KT_HI (OFF_QT_LO + (size_t)(1u<<20))
#define OFF_KT_LO (OFF_KT_HI + (size_t)(1u<<20))
#define OFF_WVBF  (OFF_KT_LO + (size_t)(1u<<20))     // [256][256] bf16 = 128KB
#define OFF_WQH   (OFF_WVBF + (size_t)(128*1024))    // 16KB each
#define OFF_WQL   (OFF_WQH + (size_t)(16*1024))
#define OFF_WKH   (OFF_WQL + (size_t)(16*1024))
#define OFF_WKL   (OFF_WKH + (size_t)(16*1024))

__device__ __forceinline__ unsigned short f2bf(float f) {
    __hip_bfloat16 h = __float2bfloat16(f);
    return *(unsigned short*)&h;
}
__device__ __forceinline__ float bf2f(unsigned short u) {
    return __bfloat162float(*(__hip_bfloat16*)&u);
}
__device__ __forceinline__ unsigned pk2(float a, float b) {
    return (unsigned)f2bf(a) | ((unsigned)f2bf(b) << 16);
}
union S8U { u32x4 u; short8 s; };

#define Z16 {0.f,0.f,0.f,0.f,0.f,0.f,0.f,0.f,0.f,0.f,0.f,0.f,0.f,0.f,0.f,0.f}
#define MFMA32 __builtin_amdgcn_mfma_f32_32x32x16_bf16

// ---------- wprep: Wv->bf16 [d][c]; Wq/Wk -> hi/lo packed B-frag layout ----------
__global__ __launch_bounds__(256) void wprep(const float* __restrict__ Wq,
                                             const float* __restrict__ Wk,
                                             const float* __restrict__ Wv,
                                             unsigned short* __restrict__ wvbf,
                                             unsigned short* __restrict__ wqh,
                                             unsigned short* __restrict__ wql,
                                             unsigned short* __restrict__ wkh,
                                             unsigned short* __restrict__ wkl)
{
    const int b = blockIdx.x;
    if (b < 64) {
        int i = b * 1024 + threadIdx.x * 4;
        f32x4 w = *(const f32x4*)(Wv + i);
        u32x2 pk;
        pk[0] = pk2(w[0], w[1]);
        pk[1] = pk2(w[2], w[3]);
        *(u32x2*)(wvbf + i) = pk;
    } else {
        const float* Wsrc = (b == 64) ? Wq : Wk;
        float scale = (b == 64) ? LOG2E : 1.f;
        unsigned short* oh = (b == 64) ? wqh : wkh;
        unsigned short* ol = (b == 64) ? wql : wkl;
        int t = threadIdx.x;
#pragma unroll
        for (int ii = 0; ii < 4; ii++) {
            int ent = t * 4 + ii;                 // ent = (kc*2+h)*32 + m
            int m = ent & 31, hh = (ent >> 5) & 1, kc = ent >> 6;
#pragma unroll
            for (int e = 0; e < 8; e++) {
                int c = kc * 16 + hh * 8 + e;
                float wv = Wsrc[m * 256 + c] * scale;
                unsigned short wh = f2bf(wv);
                oh[ent * 8 + e] = wh;
                ol[ent * 8 + e] = f2bf(wv - bf2f(wh));
            }
        }
    }
}

// ---------- fused QKV projection: x-tile in LDS, hi/lo frags in regs ----------
__global__ __launch_bounds__(256) void qkv_fused(
    const float* __restrict__ x,
    const unsigned short* __restrict__ wqh, const unsigned short* __restrict__ wql,
    const unsigned short* __restrict__ wkh, const unsigned short* __restrict__ wkl,
    const unsigned short* __restrict__ wvbf,
    const float* __restrict__ bq, const float* __restrict__ bk, const float* __restrict__ bv,
    unsigned short* __restrict__ qt_hi, unsigned short* __restrict__ qt_lo,
    unsigned short* __restrict__ kt_hi, unsigned short* __restrict__ kt_lo,
    unsigned short* __restrict__ V)
{
    const int tid = threadIdx.x;
    const int bidx = blockIdx.x;
    const int n = bidx >> 7, t0 = (bidx & 127) * 32;
    const int w = tid >> 6, l = tid & 63;
    const int l31 = l & 31, h = l >> 5;

    __shared__ float xs[256 * 36];   // [c][t] f32, pitch 36 dwords

    {
        const int c0 = tid >> 3;           // 0..31
        const int tq = (tid & 7) * 4;      // t offset
        const float* xp = x + ((size_t)n * 256 + c0) * S_LEN + t0 + tq;
#pragma unroll
        for (int p = 0; p < 8; p++) {
            f32x4 v = *(const f32x4*)(xp + (size_t)p * 32 * S_LEN);
            *(f32x4*)(&xs[(c0 + p * 32) * 36 + tq]) = v;
        }
    }
    __syncthreads();

    if (w < 2) {
        // Q (w=0) or K (w=1) projection: split-bf16, 3 MFMAs per k-step
        const unsigned short* WH = w ? wkh : wqh;
        const unsigned short* WL = w ? wkl : wql;
        f32x16 a = Z16;
#pragma unroll
        for (int kc = 0; kc < 16; kc++) {
            short8 ah, al;
#pragma unroll
            for (int e = 0; e < 8; e++) {
                float f = xs[(kc * 16 + h * 8 + e) * 36 + l31];
                unsigned short hb = f2bf(f);
                ah[e] = (short)hb;
                al[e] = (short)f2bf(f - bf2f(hb));
            }
            const short8 bh = *(const short8*)(WH + ((kc * 2 + h) * 32 + l31) * 8);
            const short8 bl = *(const short8*)(WL + ((kc * 2 + h) * 32 + l31) * 8);
            a = MFMA32(ah, bh, a, 0, 0, 0);
            a = MFMA32(al, bh, a, 0, 0, 0);
            a = MFMA32(ah, bl, a, 0, 0, 0);
        }
        float bias = w ? bk[l31] : bq[l31] * LOG2E;
        unsigned short* oh = w ? kt_hi : qt_hi;
        unsigned short* ol = w ? kt_lo : qt_lo;
#pragma unroll
        for (int r = 0; r < 16; r++) {
            int trow = (r & 3) + 8 * (r >> 2) + 4 * h;
            size_t o = ((size_t)n * S_LEN + t0 + trow) * 32 + l31;
            float v = a[r] + bias;
            unsigned short vh = f2bf(v);
            oh[o] = vh;
            ol[o] = f2bf(v - bf2f(vh));
        }
    } else {
        // V projection (w=2: d 0..127, w=3: d 128..255), bf16 hi only
        const int dh = w - 2;
        f32x16 acc[4];
#pragma unroll
        for (int dt = 0; dt < 4; dt++) acc[dt] = (f32x16)Z16;
#pragma unroll
        for (int kc = 0; kc < 16; kc++) {
            short8 ah;
#pragma unroll
            for (int e = 0; e < 8; e++)
                ah[e] = (short)f2bf(xs[(kc * 16 + h * 8 + e) * 36 + l31]);
#pragma unroll
            for (int dt = 0; dt < 4; dt++) {
                const short8 b = *(const short8*)(wvbf +
                    (size_t)(dh * 128 + dt * 32 + l31) * 256 + kc * 16 + h * 8);
                acc[dt] = MFMA32(ah, b, acc[dt], 0, 0, 0);
            }
        }
#pragma unroll
        for (int dt = 0; dt < 4; dt++) {
            int d = dh * 128 + dt * 32 + l31;
            float bvv = bv[d];
            unsigned short* vp = V + ((size_t)n * 256 + d) * S_LEN + t0;
#pragma unroll
            for (int g = 0; g < 4; g++) {
                u32x2 pkv;
                pkv[0] = pk2(acc[dt][4*g+0] + bvv, acc[dt][4*g+1] + bvv);
                pkv[1] = pk2(acc[dt][4*g+2] + bvv, acc[dt][4*g+3] + bvv);
                *(u32x2*)(vp + 8 * g + 4 * h) = pkv;
            }
        }
    }
}

// ---------- flash attention: barrier-free main loop, V/K direct from L2 ----------
__global__ __launch_bounds__(512, 2) void attn(
    const unsigned short* __restrict__ qt_hi, const unsigned short* __restrict__ qt_lo,
    const unsigned short* __restrict__ kt_hi, const unsigned short* __restrict__ kt_lo,
    const unsigned short* __restrict__ V, const float* __restrict__ x,
    const float* __restrict__ gamma, float* __restrict__ out)
{
    const int bid = blockIdx.x;
    const int n = bid & 3;                 // n pinned per XCD pair
    const int S0 = (bid >> 2) * 64;
    const int tid = threadIdx.x;
    const int w = tid >> 6, l = tid & 63;
    const int i = w & 1, q = w >> 1;       // s-chunk, t-quarter
    const int l31 = l & 31, h = l >> 5;

    __shared__ float mrg[2][8192];         // 64KB merge buffer (end only)
    __shared__ float mlds[4][2][2][32];

    const size_t qb = ((size_t)n * S_LEN + S0 + i * 32 + l31) * 32 + 8 * h;
    const short8 qh0 = *(const short8*)(qt_hi + qb);
    const short8 qh1 = *(const short8*)(qt_hi + qb + 16);
    const short8 ql0 = *(const short8*)(qt_lo + qb);
    const short8 ql1 = *(const short8*)(qt_lo + qb + 16);

    f32x16 acc[8];
#pragma unroll
    for (int dt = 0; dt < 8; dt++) acc[dt] = (f32x16)Z16;
    float m_run = -__builtin_inff(), l_run = 0.f;

    const unsigned short* Kh = kt_hi + (size_t)n * S_LEN * 32;
    const unsigned short* Kl = kt_lo + (size_t)n * S_LEN * 32;
    const unsigned short* Vn = V + (size_t)n * 256 * S_LEN;

    size_t kb = (size_t)(q * 1024 + l31) * 32 + 8 * h;
    short8 kh0 = *(const short8*)(Kh + kb), kh1 = *(const short8*)(Kh + kb + 16);
    short8 kl0 = *(const short8*)(Kl + kb), kl1 = *(const short8*)(Kl + kb + 16);

    for (int it = 0; it < 32; ++it) {
        const int t0 = q * 1024 + it * 32;

        // swapped QK^T: D[t][s], s = l31 lane-local
        f32x16 sD = Z16;
        sD = MFMA32(kh0, qh0, sD, 0, 0, 0);
        sD = MFMA32(kh0, ql0, sD, 0, 0, 0);
        sD = MFMA32(kl0, qh0, sD, 0, 0, 0);
        sD = MFMA32(kh1, qh1, sD, 0, 0, 0);
        sD = MFMA32(kh1, ql1, sD, 0, 0, 0);
        sD = MFMA32(kl1, qh1, sD, 0, 0, 0);

        // prefetch next K tile (covers full iter of latency)
        if (it < 31) {
            kb += 1024;
            kh0 = *(const short8*)(Kh + kb); kh1 = *(const short8*)(Kh + kb + 16);
            kl0 = *(const short8*)(Kl + kb); kl1 = *(const short8*)(Kl + kb + 16);
        }

        // online softmax (log2 domain), defer-max
        float a0 = fmaxf(sD[0], sD[1]),   a1 = fmaxf(sD[2], sD[3]);
        float a2 = fmaxf(sD[4], sD[5]),   a3 = fmaxf(sD[6], sD[7]);
        float a4 = fmaxf(sD[8], sD[9]),   a5 = fmaxf(sD[10], sD[11]);
        float a6 = fmaxf(sD[12], sD[13]), a7 = fmaxf(sD[14], sD[15]);
        float tmax = fmaxf(fmaxf(fmaxf(a0, a1), fmaxf(a2, a3)),
                           fmaxf(fmaxf(a4, a5), fmaxf(a6, a7)));
        tmax = fmaxf(tmax, __shfl_xor(tmax, 32));
        if (!__all(tmax <= m_run + 11.0f)) {
            float mn = fmaxf(m_run, tmax);
            float al = exp2f(m_run - mn);
#pragma unroll
            for (int dt = 0; dt < 8; dt++) acc[dt] *= al;
            l_run *= al;
            m_run = mn;
        }
        float pe[16];
#pragma unroll
        for (int r = 0; r < 16; r++) pe[r] = exp2f(sD[r] - m_run);
        float ls = ((pe[0] + pe[1]) + (pe[2] + pe[3])) + ((pe[4] + pe[5]) + (pe[6] + pe[7]))
                 + ((pe[8] + pe[9]) + (pe[10] + pe[11])) + ((pe[12] + pe[13]) + (pe[14] + pe[15]));
        ls += __shfl_xor(ls, 32);
        l_run += ls;

        // P -> bf16 A/B fragments in-register (pk pairs + xor-32 exchange)
        unsigned pb[8];
#pragma unroll
        for (int i2 = 0; i2 < 8; i2++) pb[i2] = pk2(pe[2 * i2], pe[2 * i2 + 1]);
        short8 pa[2];
#pragma unroll
        for (int c = 0; c < 2; c++) {
            unsigned s0 = h ? pb[4 * c + 0] : pb[4 * c + 2];
            unsigned s1 = h ? pb[4 * c + 1] : pb[4 * c + 3];
            unsigned r0 = __shfl_xor(s0, 32);
            unsigned r1 = __shfl_xor(s1, 32);
            S8U cv;
            cv.u[0] = h ? r0 : pb[4 * c + 0];
            cv.u[1] = h ? r1 : pb[4 * c + 1];
            cv.u[2] = h ? pb[4 * c + 2] : r0;
            cv.u[3] = h ? pb[4 * c + 3] : r1;
            pa[c] = cv.s;
        }

        // PV: V fragments direct from global (L2/L1-hot), 1-dt lookahead
        const unsigned short* vt = Vn + t0 + 8 * h;
        short8 v0 = *(const short8*)(vt + (size_t)l31 * S_LEN);
        short8 v1 = *(const short8*)(vt + (size_t)l31 * S_LEN + 16);
        __builtin_amdgcn_s_setprio(1);
#pragma unroll
        for (int dt = 0; dt < 8; dt++) {
            short8 n0 = v0, n1 = v1;
            if (dt < 7) {
                n0 = *(const short8*)(vt + (size_t)(dt * 32 + 32 + l31) * S_LEN);
                n1 = *(const short8*)(vt + (size_t)(dt * 32 + 32 + l31) * S_LEN + 16);
            }
            acc[dt] = MFMA32(v0, pa[0], acc[dt], 0, 0, 0);
            acc[dt] = MFMA32(v1, pa[1], acc[dt], 0, 0, 0);
            v0 = n0; v1 = n1;
        }
        __builtin_amdgcn_s_setprio(0);
    }

    // ---- merge quarters ----
    if (h == 0) { mlds[q][i][0][l31] = m_run; mlds[q][i][1][l31] = l_run; }
    __syncthreads();

    float M = 0.f, rden = 0.f;
    if (q == 0) {
        float m0 = mlds[0][i][0][l31], m1 = mlds[1][i][0][l31];
        float m2 = mlds[2][i][0][l31], m3 = mlds[3][i][0][l31];
        M = fmaxf(fmaxf(m0, m1), fmaxf(m2, m3));
        rden = mlds[0][i][1][l31] * exp2f(m0 - M) + mlds[1][i][1][l31] * exp2f(m1 - M)
             + mlds[2][i][1][l31] * exp2f(m2 - M) + mlds[3][i][1][l31] * exp2f(m3 - M);
        rden = 1.f / rden;
        float sc = exp2f(m_run - M);
#pragma unroll
        for (int dt = 0; dt < 8; dt++) acc[dt] *= sc;
    }
#pragma unroll
    for (int r = 1; r < 4; r++) {
        if (q == r) {
            float* mb = &mrg[i][0];
#pragma unroll
            for (int dt = 0; dt < 8; dt++)
#pragma unroll
                for (int qd = 0; qd < 4; qd++) {
                    f32x4 v = { acc[dt][4*qd], acc[dt][4*qd+1], acc[dt][4*qd+2], acc[dt][4*qd+3] };
                    *(f32x4*)(mb + (dt * 4 + qd) * 256 + l * 4) = v;
                }
        }
        __syncthreads();
        if (q == 0) {
            float sc = exp2f(mlds[r][i][0][l31] - M);
            const float* mb = &mrg[i][0];
#pragma unroll
            for (int dt = 0; dt < 8; dt++)
#pragma unroll
                for (int qd = 0; qd < 4; qd++) {
                    f32x4 v = *(const f32x4*)(mb + (dt * 4 + qd) * 256 + l * 4);
                    acc[dt][4*qd]   += v[0] * sc;
                    acc[dt][4*qd+1] += v[1] * sc;
                    acc[dt][4*qd+2] += v[2] * sc;
                    acc[dt][4*qd+3] += v[3] * sc;
                }
        }
        __syncthreads();
    }

    if (q == 0) {
        const float g = gamma[0];
        const int s = S0 + i * 32 + l31;
#pragma unroll
        for (int dt = 0; dt < 8; dt++)
#pragma unroll
            for (int r2 = 0; r2 < 16; r2++) {
                int d = dt * 32 + (r2 & 3) + 8 * (r2 >> 2) + 4 * h;
                size_t idx = ((size_t)n * 256 + d) * S_LEN + s;
                out[idx] = x[idx] + g * acc[dt][r2] * rden;
            }
    }
}

extern "C" void kernel_launch(void* const* d_in, const int* in_sizes, int n_in,
                              void* d_out, int out_size, void* d_ws, size_t ws_size,
                              hipStream_t stream) {
    const float* x     = (const float*)d_in[0];
    const float* Wq    = (const float*)d_in[1];
    const float* bq    = (const float*)d_in[2];
    const float* Wk    = (const float*)d_in[3];
    const float* bk    = (const float*)d_in[4];
    const float* Wv    = (const float*)d_in[5];
    const float* bv    = (const float*)d_in[6];
    const float* gamma = (const float*)d_in[7];
    float* out = (float*)d_out;

    unsigned char* ws = (unsigned char*)d_ws;
    unsigned short* V     = (unsigned short*)(ws + OFF_V);
    unsigned short* qt_hi = (unsigned short*)(ws + OFF_QT_HI);
    unsigned short* qt_lo = (unsigned short*)(ws + OFF_QT_LO);
    unsigned short* kt_hi = (unsigned short*)(ws + OFF_KT_HI);
    unsigned short* kt_lo = (unsigned short*)(ws + OFF_KT_LO);
    unsigned short* wvbf  = (unsigned short*)(ws + OFF_WVBF);
    unsigned short* wqh   = (unsigned short*)(ws + OFF_WQH);
    unsigned short* wql   = (unsigned short*)(ws + OFF_WQL);
    unsigned short* wkh   = (unsigned short*)(ws + OFF_WKH);
    unsigned short* wkl   = (unsigned short*)(ws + OFF_WKL);

    wprep<<<dim3(66), dim3(256), 0, stream>>>(Wq, Wk, Wv, wvbf, wqh, wql, wkh, wkl);
    qkv_fused<<<dim3(512), dim3(256), 0, stream>>>(x, wqh, wql, wkh, wkl, wvbf,
                                                   bq, bk, bv,
                                                   qt_hi, qt_lo, kt_hi, kt_lo, V);
    attn<<<dim3(256), dim3(512), 0, stream>>>(qt_hi, qt_lo, kt_hi, kt_lo, V,
                                              x, gamma, out);
}